// Round 5
// baseline (89.364 us; speedup 1.0000x reference)
//
#include <hip/hip_runtime.h>
#include <hip/hip_bf16.h>

#define HW   3136   // 56*56
#define WID  56
#define CIN  256
#define NH   8
#define HD   32
#define KK   49
#define NW   8

// ws layout (element offsets):
//   kmap  f32  [2*NH*HW*HD]            @ float offset 0
//   qmap  bf16 [2*NH*HW*HD]            @ byte 6,422,528
//   vmap  bf16                          @ byte 9,633,792
//   xT_hi bf16 [2*HW*CIN]               @ byte 12,845,056
//   xT_lo bf16                          @ byte 16,056,320   (end 19,267,584 = proven ws floor)
#define MAPN  (2 * NH * HW * HD)   // elements per map (=1605632)
#define QOFFB 6422528
#define VOFFB 9633792
#define XHOFFB 12845056
#define XLOFFB 16056320
// W split lives in d_out (ushort): whi @ 0, wlo @ 768*256
#define WELEM (768 * 256)

#define SROWS 196   // 14*14 staged halo window
#define QSTR  36    // floats per staged q row
#define VSTR  40    // ushorts per staged v row

typedef short  bf16x8 __attribute__((ext_vector_type(8)));
typedef float  f32x4  __attribute__((ext_vector_type(4)));

__device__ __forceinline__ unsigned f2bf(float x) {        // RNE f32->bf16 bits
    unsigned u = __float_as_uint(x);
    return (u + 0x7fffu + ((u >> 16) & 1u)) >> 16;
}
__device__ __forceinline__ float bfb2f(unsigned h)  { return __uint_as_float(h << 16); }
__device__ __forceinline__ float bf2f_lo(unsigned u){ return __uint_as_float(u << 16); }
__device__ __forceinline__ float bf2f_hi(unsigned u){ return __uint_as_float(u & 0xffff0000u); }

// ---------------------------------------------------------------------------
// xt_kernel: x[b][c][p] f32 -> xT_hi/xT_lo[(b*HW+p)*CIN + c] bf16 (transpose+split)
// ---------------------------------------------------------------------------
__global__ __launch_bounds__(256) void xt_kernel(
    const float* __restrict__ x,
    unsigned short* __restrict__ xh, unsigned short* __restrict__ xl)
{
    __shared__ float xs[32][65];
    const int b  = blockIdx.z;
    const int c0 = blockIdx.y * 32;
    const int p0 = blockIdx.x * 64;
    const int t  = threadIdx.x;
    const int pl = t & 63, cb = t >> 6;
    #pragma unroll
    for (int i = 0; i < 8; ++i)
        xs[cb + 4 * i][pl] = x[(size_t)(b * CIN + c0 + cb + 4 * i) * HW + p0 + pl];
    __syncthreads();
    const int pw = t >> 2, cg = t & 3;
    unsigned h[8], l[8];
    #pragma unroll
    for (int e = 0; e < 8; ++e) {
        float f = xs[cg * 8 + e][pw];
        h[e] = f2bf(f);
        l[e] = f2bf(f - bfb2f(h[e]));
    }
    uint4 uh = make_uint4(h[0] | (h[1] << 16), h[2] | (h[3] << 16),
                          h[4] | (h[5] << 16), h[6] | (h[7] << 16));
    uint4 ul = make_uint4(l[0] | (l[1] << 16), l[2] | (l[3] << 16),
                          l[4] | (l[5] << 16), l[6] | (l[7] << 16));
    const size_t idx = (size_t)(b * HW + p0 + pw) * CIN + c0 + cg * 8;
    *(uint4*)&xh[idx] = uh;
    *(uint4*)&xl[idx] = ul;
}

// ---------------------------------------------------------------------------
// wbf_kernel: Wk|Wq|Wv f32 [256][256] -> Whi/Wlo bf16 [768][256] (in d_out)
// ---------------------------------------------------------------------------
__global__ __launch_bounds__(256) void wbf_kernel(
    const float* __restrict__ Wk, const float* __restrict__ Wq,
    const float* __restrict__ Wv,
    unsigned short* __restrict__ whi, unsigned short* __restrict__ wlo)
{
    const int tid  = blockIdx.x * 256 + threadIdx.x;   // 0..24575
    const int mrow = tid >> 5, cg = tid & 31;
    const int proj = mrow >> 8, msub = mrow & 255;
    const float* Wp  = (proj == 0) ? Wk : (proj == 1 ? Wq : Wv);
    const float* src = Wp + (size_t)msub * CIN + cg * 8;
    float f[8];
    *(float4*)&f[0] = *(const float4*)src;
    *(float4*)&f[4] = *(const float4*)(src + 4);
    unsigned h[8], l[8];
    #pragma unroll
    for (int e = 0; e < 8; ++e) {
        h[e] = f2bf(f[e]);
        l[e] = f2bf(f[e] - bfb2f(h[e]));
    }
    uint4 uh = make_uint4(h[0] | (h[1] << 16), h[2] | (h[3] << 16),
                          h[4] | (h[5] << 16), h[6] | (h[7] << 16));
    uint4 ul = make_uint4(l[0] | (l[1] << 16), l[2] | (l[3] << 16),
                          l[4] | (l[5] << 16), l[6] | (l[7] << 16));
    *(uint4*)&whi[(size_t)mrow * CIN + cg * 8] = uh;
    *(uint4*)&wlo[(size_t)mrow * CIN + cg * 8] = ul;
}

// ---------------------------------------------------------------------------
// proj_kernel (split-bf16 MFMA): OUT[m][p] = sum_c W[m][c] * x[c][p]
//   OUT = Whi*xhi + Whi*xlo + Wlo*xhi   (f32-exact to ~2^-18)
// Block: 64 pix x 64 m, 4 waves.  xT hi/lo tiles staged in LDS (XOR swizzle);
// W frags read per-wave from global (L1/L2-hot, 786KB total).
// D layout: col(lane&15)=pixel, row((lane>>4)*4+reg)=m -> 4 consecutive d/lane.
// ---------------------------------------------------------------------------
__global__ __launch_bounds__(256, 2) void proj_kernel(
    const unsigned short* __restrict__ xh,
    const unsigned short* __restrict__ xl,
    const unsigned short* __restrict__ whi,
    const unsigned short* __restrict__ wlo,
    float* __restrict__ kmap,
    unsigned short* __restrict__ qmap,
    unsigned short* __restrict__ vmap)
{
    __shared__ unsigned short Xh[64 * 256];   // 32 KB
    __shared__ unsigned short Xl[64 * 256];   // 32 KB

    const int bx = blockIdx.x;          // 0..97
    const int b  = bx / 49;
    const int p0 = (bx % 49) * 64;
    const int m0 = blockIdx.y * 64;
    const int proj  = m0 >> 8;          // block-uniform
    const int msub0 = m0 & 255;

    const int t    = threadIdx.x;
    const int lane = t & 63;
    const int w    = t >> 6;

    // stage xT hi/lo tiles, swizzled: byte = p*512 + ((cg*16) ^ ((p&7)<<4))
    #pragma unroll
    for (int i = 0; i < 8; ++i) {
        int chunk = t + i * 256;
        int p = chunk >> 5, cg = chunk & 31;
        size_t gi = (size_t)(b * HW + p0 + p) * CIN + cg * 8;
        unsigned off = p * 512 + ((cg * 16) ^ ((p & 7) << 4));
        *(uint4*)((char*)Xh + off) = *(const uint4*)&xh[gi];
        *(uint4*)((char*)Xl + off) = *(const uint4*)&xl[gi];
    }
    __syncthreads();

    const int l15  = lane & 15;
    const int kg   = lane >> 4;                 // 0..3
    const int prow = w * 16 + l15;
    const int swzc = (l15 & 7) << 4;
    const char* XhB = (const char*)Xh + prow * 512;
    const char* XlB = (const char*)Xl + prow * 512;
    const unsigned short* WhR = whi + (size_t)(m0 + l15) * CIN + kg * 8;
    const unsigned short* WlR = wlo + (size_t)(m0 + l15) * CIN + kg * 8;

    f32x4 a0 = {0.f, 0.f, 0.f, 0.f};
    f32x4 a1 = a0, a2 = a0, a3 = a0;

    #pragma unroll
    for (int kk = 0; kk < 8; ++kk) {
        unsigned boff = (unsigned)((kk * 64 + kg * 16) ^ swzc);
        bf16x8 bh = *(const bf16x8*)(XhB + boff);
        bf16x8 bl = *(const bf16x8*)(XlB + boff);
        #define STEP(ACC, MF) { \
            bf16x8 ah = *(const bf16x8*)(WhR + (MF) * 16 * CIN + kk * 32); \
            bf16x8 al = *(const bf16x8*)(WlR + (MF) * 16 * CIN + kk * 32); \
            ACC = __builtin_amdgcn_mfma_f32_16x16x32_bf16(ah, bh, ACC, 0, 0, 0); \
            ACC = __builtin_amdgcn_mfma_f32_16x16x32_bf16(ah, bl, ACC, 0, 0, 0); \
            ACC = __builtin_amdgcn_mfma_f32_16x16x32_bf16(al, bh, ACC, 0, 0, 0); }
        STEP(a0, 0) STEP(a1, 1) STEP(a2, 2) STEP(a3, 3)
        #undef STEP
    }

    const int pix = p0 + prow;
    #define ST(ACC, MF) { \
        int msub = msub0 + (MF) * 16 + kg * 4; \
        int nloc = msub >> 5, d = msub & 31; \
        size_t base = ((size_t)(b * NH + nloc) * HW + pix) * HD + d; \
        if (proj == 0) { \
            *(float4*)&kmap[base] = make_float4(ACC[0], ACC[1], ACC[2], ACC[3]); \
        } else { \
            uint2 u; \
            u.x = f2bf(ACC[0]) | (f2bf(ACC[1]) << 16); \
            u.y = f2bf(ACC[2]) | (f2bf(ACC[3]) << 16); \
            unsigned short* mp = (proj == 1) ? qmap : vmap; \
            *(uint2*)&mp[base] = u; } }
    ST(a0, 0) ST(a1, 1) ST(a2, 2) ST(a3, 3)
    #undef ST
}

// ---------------------------------------------------------------------------
// attn_kernel: block = (b, n, 8x8 pixel tile), 512 threads.
// k map f32; q/v maps bf16.
// ---------------------------------------------------------------------------
__global__ __launch_bounds__(512, 4) void attn_kernel(
    const float* __restrict__ kmap,
    const unsigned short* __restrict__ qmap,
    const unsigned short* __restrict__ vmap,
    const float* __restrict__ rel_h,
    const float* __restrict__ rel_w,
    float* __restrict__ out)
{
    __shared__ float          stq[SROWS * QSTR];   // 28224 B
    __shared__ unsigned short stv[SROWS * VSTR];   // 15680 B
    __shared__ unsigned short Llds[KK][64];        //  6272 B
    __shared__ float          rhw[14][64];         //  3584 B
    __shared__ float          mpart[NW][64];       //  2048 B
    __shared__ float          spart[NW][64];       //  2048 B

    const int bid = blockIdx.x;
    const int swz = (bid & 7) * 98 + (bid >> 3);   // XCD-bijective (784 = 8*98)
    const int b    = swz / 392;
    const int rem  = swz - b * 392;
    const int n    = rem / 49;
    const int tile = rem - n * 49;
    const int ty0  = (tile / 7) * 8;
    const int tx0  = (tile % 7) * 8;

    const int t    = threadIdx.x;
    const int lane = t & 63;
    const int w    = t >> 6;
    const int py   = lane >> 3;
    const int px   = lane & 7;
    const int pix  = (ty0 + py) * WID + tx0 + px;

    const size_t mb = (size_t)(b * NH + n) * HW;

    // ---- stage q (bf16->f32) and v (bf16 copy) ----
    #pragma unroll
    for (int kk = 0; kk < 2; ++kk) {
        int f = t + kk * 512;
        if (f < SROWS * 4) {
            int sp = f >> 2, ch = f & 3;
            int sy = sp / 14, sx = sp - sy * 14;
            int gy = ty0 + sy - 3, gx = tx0 + sx - 3;
            uint4 q = make_uint4(0, 0, 0, 0), v = make_uint4(0, 0, 0, 0);
            if ((unsigned)gy < 56u && (unsigned)gx < 56u) {
                size_t rec = (mb + gy * WID + gx) * HD + ch * 8;
                q = *(const uint4*)&qmap[rec];
                v = *(const uint4*)&vmap[rec];
            }
            float* qd = &stq[sp * QSTR + ch * 8];
            *(float4*)qd       = make_float4(bf2f_lo(q.x), bf2f_hi(q.x),
                                             bf2f_lo(q.y), bf2f_hi(q.y));
            *(float4*)(qd + 4) = make_float4(bf2f_lo(q.z), bf2f_hi(q.z),
                                             bf2f_lo(q.w), bf2f_hi(q.w));
            *(uint4*)&stv[sp * VSTR + ch * 8] = v;
        }
    }

    // ---- center key vector (f32) ----
    float kc[HD];
    const size_t krec = (mb + pix) * HD;
    #pragma unroll
    for (int c4 = 0; c4 < 8; ++c4) {
        float4 kv = *(const float4*)&kmap[krec + c4 * 4];
        kc[c4 * 4 + 0] = kv.x; kc[c4 * 4 + 1] = kv.y;
        kc[c4 * 4 + 2] = kv.z; kc[c4 * 4 + 3] = kv.w;
    }

    // ---- rel bias dots, once per block (waves 0..6) ----
    if (w < 7) {
        float a = 0.f, c = 0.f;
        #pragma unroll
        for (int dd = 0; dd < 16; ++dd) {
            a += rel_h[(n * 7 + w) * 16 + dd] * kc[dd];
            c += rel_w[(n * 7 + w) * 16 + dd] * kc[16 + dd];
        }
        rhw[w][lane]     = a;
        rhw[7 + w][lane] = c;
    }
    __syncthreads();

    // ---- QK: wave w owns cells k = w + 8c ----
    const int spc = py * 14 + px;
    float l[7];
    float lm = -1e30f;
    #pragma unroll
    for (int c = 0; c < 7; ++c) {
        const int k = w + c * NW;
        if (k < KK) {                       // wave-uniform
            int i = k / 7, j = k - i * 7;
            int sp = spc + i * 14 + j;
            float dot = 0.f;
            #pragma unroll
            for (int c4 = 0; c4 < 8; ++c4) {
                float4 qv = *(const float4*)&stq[sp * QSTR + c4 * 4];
                dot += kc[c4 * 4 + 0] * qv.x + kc[c4 * 4 + 1] * qv.y
                     + kc[c4 * 4 + 2] * qv.z + kc[c4 * 4 + 3] * qv.w;
            }
            float lv = rhw[i][lane] + rhw[7 + j][lane] + dot;
            l[c] = lv;
            lm = fmaxf(lm, lv);
        } else {
            l[c] = -1e30f;
        }
    }
    mpart[w][lane] = lm;
    __syncthreads();

    float m = mpart[0][lane];
    #pragma unroll
    for (int ww = 1; ww < NW; ++ww) m = fmaxf(m, mpart[ww][lane]);

    float lsum = 0.f;
    #pragma unroll
    for (int c = 0; c < 7; ++c) {
        const int k = w + c * NW;
        if (k < KK) {
            float e = __expf(l[c] - m);
            lsum += e;
            Llds[k][lane] = (unsigned short)f2bf(e);
        }
    }
    spart[w][lane] = lsum;
    __syncthreads();

    float s = spart[0][lane];
    #pragma unroll
    for (int ww = 1; ww < NW; ++ww) s += spart[ww][lane];
    const float inv = 1.f / s;

    // ---- PV: wave w owns d = 4w..4w+3 ----
    const int d0 = w * 4;
    float o0 = 0.f, o1 = 0.f, o2 = 0.f, o3 = 0.f;
    #pragma unroll
    for (int k = 0; k < KK; ++k) {
        const int i = k / 7, j = k - i * 7;
        int sp = spc + i * 14 + j;
        float e = bfb2f((unsigned)Llds[k][lane]);
        uint2 vv = *(const uint2*)&stv[sp * VSTR + d0];
        o0 += e * bf2f_lo(vv.x);
        o1 += e * bf2f_hi(vv.x);
        o2 += e * bf2f_lo(vv.y);
        o3 += e * bf2f_hi(vv.y);
    }
    const size_t ob = ((size_t)(b * NH + n) * HD + d0) * HW + pix;
    out[ob]          = o0 * inv;
    out[ob + HW]     = o1 * inv;
    out[ob + 2 * HW] = o2 * inv;
    out[ob + 3 * HW] = o3 * inv;
}

extern "C" void kernel_launch(void* const* d_in, const int* in_sizes, int n_in,
                              void* d_out, int out_size, void* d_ws, size_t ws_size,
                              hipStream_t stream) {
    const float* x     = (const float*)d_in[0];
    const float* Wk    = (const float*)d_in[1];
    const float* Wq    = (const float*)d_in[2];
    const float* Wv    = (const float*)d_in[3];
    const float* rel_h = (const float*)d_in[4];
    const float* rel_w = (const float*)d_in[5];

    char* wsb = (char*)d_ws;
    float*          kmap = (float*)wsb;
    unsigned short* qmap = (unsigned short*)(wsb + QOFFB);
    unsigned short* vmap = (unsigned short*)(wsb + VOFFB);
    unsigned short* xh   = (unsigned short*)(wsb + XHOFFB);
    unsigned short* xl   = (unsigned short*)(wsb + XLOFFB);

    // W split scratch lives in d_out; attn fully overwrites d_out afterwards.
    unsigned short* whi = (unsigned short*)d_out;
    unsigned short* wlo = whi + WELEM;
    float* out = (float*)d_out;

    hipLaunchKernelGGL(xt_kernel,  dim3(49, 8, 2), dim3(256), 0, stream, x, xh, xl);
    hipLaunchKernelGGL(wbf_kernel, dim3(96),       dim3(256), 0, stream,
                       Wk, Wq, Wv, whi, wlo);
    hipLaunchKernelGGL(proj_kernel, dim3(98, 12),  dim3(256), 0, stream,
                       xh, xl, whi, wlo, kmap, qmap, vmap);
    hipLaunchKernelGGL(attn_kernel, dim3(784),     dim3(512), 0, stream,
                       kmap, qmap, vmap, rel_h, rel_w, out);
}

// Round 6
// 51.801 us; speedup vs baseline: 1.7251x; 1.7251x over previous
//
#include <hip/hip_runtime.h>
#include <hip/hip_bf16.h>

#define HW   3136   // 56*56
#define WID  56
#define CIN  256
#define NH   8
#define HD   32
#define KK   49
#define NW   8

// ws layout (byte offsets):
//   kmap  f32  [2*NH*HW*HD] @ 0
//   qmap  bf16              @ 6,422,528
//   vmap  bf16              @ 9,633,792
//   xT_hi bf16 [2*HW*CIN]   @ 12,845,056
//   xT_lo bf16              @ 16,056,320   (end 19,267,584)
#define MAPN  (2 * NH * HW * HD)
#define QOFFB 6422528
#define VOFFB 9633792
#define XHOFFB 12845056
#define XLOFFB 16056320
// W split lives in d_out (ushort): whi @ 0, wlo @ 768*256
#define WELEM (768 * 256)

#define SROWS 196   // 14*14 staged halo window
#define QSTR  36    // floats per staged q row
#define VSTR  40    // ushorts per staged v row

typedef short  bf16x8 __attribute__((ext_vector_type(8)));
typedef float  f32x4  __attribute__((ext_vector_type(4)));

__device__ __forceinline__ unsigned f2bf(float x) {        // RNE f32->bf16 bits
    unsigned u = __float_as_uint(x);
    return (u + 0x7fffu + ((u >> 16) & 1u)) >> 16;
}
__device__ __forceinline__ float bfb2f(unsigned h)  { return __uint_as_float(h << 16); }
__device__ __forceinline__ float bf2f_lo(unsigned u){ return __uint_as_float(u << 16); }
__device__ __forceinline__ float bf2f_hi(unsigned u){ return __uint_as_float(u & 0xffff0000u); }

// ---------------------------------------------------------------------------
// xt_kernel: x[b][c][p] f32 -> xT_hi/xT_lo[(b*HW+p)*CIN + c] bf16 (transpose+split)
// ---------------------------------------------------------------------------
__global__ __launch_bounds__(256) void xt_kernel(
    const float* __restrict__ x,
    unsigned short* __restrict__ xh, unsigned short* __restrict__ xl)
{
    __shared__ float xs[32][65];
    const int b  = blockIdx.z;
    const int c0 = blockIdx.y * 32;
    const int p0 = blockIdx.x * 64;
    const int t  = threadIdx.x;
    const int pl = t & 63, cb = t >> 6;
    #pragma unroll
    for (int i = 0; i < 8; ++i)
        xs[cb + 4 * i][pl] = x[(size_t)(b * CIN + c0 + cb + 4 * i) * HW + p0 + pl];
    __syncthreads();
    const int pw = t >> 2, cg = t & 3;
    unsigned h[8], l[8];
    #pragma unroll
    for (int e = 0; e < 8; ++e) {
        float f = xs[cg * 8 + e][pw];
        h[e] = f2bf(f);
        l[e] = f2bf(f - bfb2f(h[e]));
    }
    uint4 uh = make_uint4(h[0] | (h[1] << 16), h[2] | (h[3] << 16),
                          h[4] | (h[5] << 16), h[6] | (h[7] << 16));
    uint4 ul = make_uint4(l[0] | (l[1] << 16), l[2] | (l[3] << 16),
                          l[4] | (l[5] << 16), l[6] | (l[7] << 16));
    const size_t idx = (size_t)(b * HW + p0 + pw) * CIN + c0 + cg * 8;
    *(uint4*)&xh[idx] = uh;
    *(uint4*)&xl[idx] = ul;
}

// ---------------------------------------------------------------------------
// wbf_kernel: Wk|Wq|Wv f32 [256][256] -> Whi/Wlo bf16 [768][256] (in d_out)
// ---------------------------------------------------------------------------
__global__ __launch_bounds__(256) void wbf_kernel(
    const float* __restrict__ Wk, const float* __restrict__ Wq,
    const float* __restrict__ Wv,
    unsigned short* __restrict__ whi, unsigned short* __restrict__ wlo)
{
    const int tid  = blockIdx.x * 256 + threadIdx.x;   // 0..24575
    const int mrow = tid >> 5, cg = tid & 31;
    const int proj = mrow >> 8, msub = mrow & 255;
    const float* Wp  = (proj == 0) ? Wk : (proj == 1 ? Wq : Wv);
    const float* src = Wp + (size_t)msub * CIN + cg * 8;
    float f[8];
    *(float4*)&f[0] = *(const float4*)src;
    *(float4*)&f[4] = *(const float4*)(src + 4);
    unsigned h[8], l[8];
    #pragma unroll
    for (int e = 0; e < 8; ++e) {
        h[e] = f2bf(f[e]);
        l[e] = f2bf(f[e] - bfb2f(h[e]));
    }
    uint4 uh = make_uint4(h[0] | (h[1] << 16), h[2] | (h[3] << 16),
                          h[4] | (h[5] << 16), h[6] | (h[7] << 16));
    uint4 ul = make_uint4(l[0] | (l[1] << 16), l[2] | (l[3] << 16),
                          l[4] | (l[5] << 16), l[6] | (l[7] << 16));
    *(uint4*)&whi[(size_t)mrow * CIN + cg * 8] = uh;
    *(uint4*)&wlo[(size_t)mrow * CIN + cg * 8] = ul;
}

// ---------------------------------------------------------------------------
// proj_kernel v2 (split-bf16 MFMA, LDS-fed): OUT[m][row] = sum_c W[m][c]*xT[row][c]
//   OUT = Whi*xhi + Whi*xlo + Wlo*xhi
// Block: 512 thr = 8 waves (2m x 4p), tile 64 m x 128 pixel-rows, BK=64.
// LDS: Xh/Xl 128x64 bf16 (16KB ea) + Wh/Wl 64x64 bf16 (8KB ea) = 48 KB.
// Row-XOR swizzle keeps both staging writes and frag reads bank-balanced.
// ---------------------------------------------------------------------------
__global__ __launch_bounds__(512, 4) void proj_kernel(
    const unsigned short* __restrict__ xh,
    const unsigned short* __restrict__ xl,
    const unsigned short* __restrict__ whi,
    const unsigned short* __restrict__ wlo,
    float* __restrict__ kmap,
    unsigned short* __restrict__ qmap,
    unsigned short* __restrict__ vmap)
{
    __shared__ unsigned short Xh[128 * 64];   // 16 KB
    __shared__ unsigned short Xl[128 * 64];   // 16 KB
    __shared__ unsigned short Wh[64 * 64];    //  8 KB
    __shared__ unsigned short Wl[64 * 64];    //  8 KB

    const int pr0 = blockIdx.x * 128;        // global pixel-row base (0..6144)
    const int m0  = blockIdx.y * 64;
    const int proj  = m0 >> 8;               // block-uniform
    const int msub0 = m0 & 255;

    const int t    = threadIdx.x;
    const int lane = t & 63;
    const int w    = t >> 6;
    const int wm   = (w >> 2) << 5;          // 0,32
    const int wp   = (w & 3) << 5;           // 0,32,64,96
    const int l15  = lane & 15;
    const int kg   = lane >> 4;
    const unsigned sz = (unsigned)(l15 & 7) << 4;

    f32x4 acc00 = {0.f, 0.f, 0.f, 0.f};
    f32x4 acc01 = acc00, acc10 = acc00, acc11 = acc00;

    // staging geometry (fixed per thread)
    const int srow  = t >> 3;                // 0..63
    const int scg   = t & 7;                 // 16B chunk within 64-c row
    const unsigned woff  = (unsigned)(srow * 128 + ((scg * 16) ^ ((srow & 7) << 4)));
    const int xrow1 = srow + 64;
    const unsigned xoff1 = (unsigned)(xrow1 * 128 + ((scg * 16) ^ ((xrow1 & 7) << 4)));

    for (int c0 = 0; c0 < CIN; c0 += 64) {
        if (c0) __syncthreads();             // LDS reuse barrier
        {
            size_t wg  = (size_t)(m0 + srow) * CIN + c0 + scg * 8;
            *(uint4*)((char*)Wh + woff) = *(const uint4*)&whi[wg];
            *(uint4*)((char*)Wl + woff) = *(const uint4*)&wlo[wg];
            size_t xg0 = (size_t)(pr0 + srow) * CIN + c0 + scg * 8;
            size_t xg1 = (size_t)(pr0 + xrow1) * CIN + c0 + scg * 8;
            *(uint4*)((char*)Xh + woff)  = *(const uint4*)&xh[xg0];
            *(uint4*)((char*)Xl + woff)  = *(const uint4*)&xl[xg0];
            *(uint4*)((char*)Xh + xoff1) = *(const uint4*)&xh[xg1];
            *(uint4*)((char*)Xl + xoff1) = *(const uint4*)&xl[xg1];
        }
        __syncthreads();

        #pragma unroll
        for (int kk = 0; kk < 2; ++kk) {
            const unsigned cb = ((unsigned)(kk * 64 + kg * 16)) ^ sz;
            const char* whb = (const char*)Wh + cb;
            const char* wlb = (const char*)Wl + cb;
            const char* xhb = (const char*)Xh + cb;
            const char* xlb = (const char*)Xl + cb;
            bf16x8 ah0 = *(const bf16x8*)(whb + (wm + l15) * 128);
            bf16x8 ah1 = *(const bf16x8*)(whb + (wm + 16 + l15) * 128);
            bf16x8 al0 = *(const bf16x8*)(wlb + (wm + l15) * 128);
            bf16x8 al1 = *(const bf16x8*)(wlb + (wm + 16 + l15) * 128);
            bf16x8 bh0 = *(const bf16x8*)(xhb + (wp + l15) * 128);
            bf16x8 bh1 = *(const bf16x8*)(xhb + (wp + 16 + l15) * 128);
            bf16x8 bl0 = *(const bf16x8*)(xlb + (wp + l15) * 128);
            bf16x8 bl1 = *(const bf16x8*)(xlb + (wp + 16 + l15) * 128);
            acc00 = __builtin_amdgcn_mfma_f32_16x16x32_bf16(ah0, bh0, acc00, 0, 0, 0);
            acc01 = __builtin_amdgcn_mfma_f32_16x16x32_bf16(ah0, bh1, acc01, 0, 0, 0);
            acc10 = __builtin_amdgcn_mfma_f32_16x16x32_bf16(ah1, bh0, acc10, 0, 0, 0);
            acc11 = __builtin_amdgcn_mfma_f32_16x16x32_bf16(ah1, bh1, acc11, 0, 0, 0);
            acc00 = __builtin_amdgcn_mfma_f32_16x16x32_bf16(ah0, bl0, acc00, 0, 0, 0);
            acc01 = __builtin_amdgcn_mfma_f32_16x16x32_bf16(ah0, bl1, acc01, 0, 0, 0);
            acc10 = __builtin_amdgcn_mfma_f32_16x16x32_bf16(ah1, bl0, acc10, 0, 0, 0);
            acc11 = __builtin_amdgcn_mfma_f32_16x16x32_bf16(ah1, bl1, acc11, 0, 0, 0);
            acc00 = __builtin_amdgcn_mfma_f32_16x16x32_bf16(al0, bh0, acc00, 0, 0, 0);
            acc01 = __builtin_amdgcn_mfma_f32_16x16x32_bf16(al0, bh1, acc01, 0, 0, 0);
            acc10 = __builtin_amdgcn_mfma_f32_16x16x32_bf16(al1, bh0, acc10, 0, 0, 0);
            acc11 = __builtin_amdgcn_mfma_f32_16x16x32_bf16(al1, bh1, acc11, 0, 0, 0);
        }
    }

    // epilogue: each lane's f32x4 = 4 consecutive m (=d) for one pixel-row
    #define ST(ACC, MI, PI) { \
        int prow = pr0 + wp + (PI) * 16 + l15; \
        int bb = (prow >= HW) ? 1 : 0; \
        int pp = prow - bb * HW; \
        int msub = msub0 + wm + (MI) * 16 + kg * 4; \
        size_t base = ((size_t)(bb * NH + (msub >> 5)) * HW + pp) * HD + (msub & 31); \
        if (proj == 0) { \
            *(float4*)&kmap[base] = make_float4(ACC[0], ACC[1], ACC[2], ACC[3]); \
        } else { \
            uint2 u; \
            u.x = f2bf(ACC[0]) | (f2bf(ACC[1]) << 16); \
            u.y = f2bf(ACC[2]) | (f2bf(ACC[3]) << 16); \
            unsigned short* mp = (proj == 1) ? qmap : vmap; \
            *(uint2*)&mp[base] = u; } }
    ST(acc00, 0, 0) ST(acc01, 0, 1) ST(acc10, 1, 0) ST(acc11, 1, 1)
    #undef ST
}

// ---------------------------------------------------------------------------
// attn_kernel: block = (b, n, 8x8 pixel tile), 512 threads.
// k map f32; q/v maps bf16.
// ---------------------------------------------------------------------------
__global__ __launch_bounds__(512, 4) void attn_kernel(
    const float* __restrict__ kmap,
    const unsigned short* __restrict__ qmap,
    const unsigned short* __restrict__ vmap,
    const float* __restrict__ rel_h,
    const float* __restrict__ rel_w,
    float* __restrict__ out)
{
    __shared__ float          stq[SROWS * QSTR];   // 28224 B
    __shared__ unsigned short stv[SROWS * VSTR];   // 15680 B
    __shared__ unsigned short Llds[KK][64];        //  6272 B
    __shared__ float          rhw[14][64];         //  3584 B
    __shared__ float          mpart[NW][64];       //  2048 B
    __shared__ float          spart[NW][64];       //  2048 B

    const int bid = blockIdx.x;
    const int swz = (bid & 7) * 98 + (bid >> 3);   // XCD-bijective (784 = 8*98)
    const int b    = swz / 392;
    const int rem  = swz - b * 392;
    const int n    = rem / 49;
    const int tile = rem - n * 49;
    const int ty0  = (tile / 7) * 8;
    const int tx0  = (tile % 7) * 8;

    const int t    = threadIdx.x;
    const int lane = t & 63;
    const int w    = t >> 6;
    const int py   = lane >> 3;
    const int px   = lane & 7;
    const int pix  = (ty0 + py) * WID + tx0 + px;

    const size_t mb = (size_t)(b * NH + n) * HW;

    // ---- stage q (bf16->f32) and v (bf16 copy) ----
    #pragma unroll
    for (int kk = 0; kk < 2; ++kk) {
        int f = t + kk * 512;
        if (f < SROWS * 4) {
            int sp = f >> 2, ch = f & 3;
            int sy = sp / 14, sx = sp - sy * 14;
            int gy = ty0 + sy - 3, gx = tx0 + sx - 3;
            uint4 q = make_uint4(0, 0, 0, 0), v = make_uint4(0, 0, 0, 0);
            if ((unsigned)gy < 56u && (unsigned)gx < 56u) {
                size_t rec = (mb + gy * WID + gx) * HD + ch * 8;
                q = *(const uint4*)&qmap[rec];
                v = *(const uint4*)&vmap[rec];
            }
            float* qd = &stq[sp * QSTR + ch * 8];
            *(float4*)qd       = make_float4(bf2f_lo(q.x), bf2f_hi(q.x),
                                             bf2f_lo(q.y), bf2f_hi(q.y));
            *(float4*)(qd + 4) = make_float4(bf2f_lo(q.z), bf2f_hi(q.z),
                                             bf2f_lo(q.w), bf2f_hi(q.w));
            *(uint4*)&stv[sp * VSTR + ch * 8] = v;
        }
    }

    // ---- center key vector (f32) ----
    float kc[HD];
    const size_t krec = (mb + pix) * HD;
    #pragma unroll
    for (int c4 = 0; c4 < 8; ++c4) {
        float4 kv = *(const float4*)&kmap[krec + c4 * 4];
        kc[c4 * 4 + 0] = kv.x; kc[c4 * 4 + 1] = kv.y;
        kc[c4 * 4 + 2] = kv.z; kc[c4 * 4 + 3] = kv.w;
    }

    // ---- rel bias dots, once per block (waves 0..6) ----
    if (w < 7) {
        float a = 0.f, c = 0.f;
        #pragma unroll
        for (int dd = 0; dd < 16; ++dd) {
            a += rel_h[(n * 7 + w) * 16 + dd] * kc[dd];
            c += rel_w[(n * 7 + w) * 16 + dd] * kc[16 + dd];
        }
        rhw[w][lane]     = a;
        rhw[7 + w][lane] = c;
    }
    __syncthreads();

    // ---- QK: wave w owns cells k = w + 8c ----
    const int spc = py * 14 + px;
    float l[7];
    float lm = -1e30f;
    #pragma unroll
    for (int c = 0; c < 7; ++c) {
        const int k = w + c * NW;
        if (k < KK) {                       // wave-uniform
            int i = k / 7, j = k - i * 7;
            int sp = spc + i * 14 + j;
            float dot = 0.f;
            #pragma unroll
            for (int c4 = 0; c4 < 8; ++c4) {
                float4 qv = *(const float4*)&stq[sp * QSTR + c4 * 4];
                dot += kc[c4 * 4 + 0] * qv.x + kc[c4 * 4 + 1] * qv.y
                     + kc[c4 * 4 + 2] * qv.z + kc[c4 * 4 + 3] * qv.w;
            }
            float lv = rhw[i][lane] + rhw[7 + j][lane] + dot;
            l[c] = lv;
            lm = fmaxf(lm, lv);
        } else {
            l[c] = -1e30f;
        }
    }
    mpart[w][lane] = lm;
    __syncthreads();

    float m = mpart[0][lane];
    #pragma unroll
    for (int ww = 1; ww < NW; ++ww) m = fmaxf(m, mpart[ww][lane]);

    float lsum = 0.f;
    #pragma unroll
    for (int c = 0; c < 7; ++c) {
        const int k = w + c * NW;
        if (k < KK) {
            float e = __expf(l[c] - m);
            lsum += e;
            Llds[k][lane] = (unsigned short)f2bf(e);
        }
    }
    spart[w][lane] = lsum;
    __syncthreads();

    float s = spart[0][lane];
    #pragma unroll
    for (int ww = 1; ww < NW; ++ww) s += spart[ww][lane];
    const float inv = 1.f / s;

    // ---- PV: wave w owns d = 4w..4w+3 ----
    const int d0 = w * 4;
    float o0 = 0.f, o1 = 0.f, o2 = 0.f, o3 = 0.f;
    #pragma unroll
    for (int k = 0; k < KK; ++k) {
        const int i = k / 7, j = k - i * 7;
        int sp = spc + i * 14 + j;
        float e = bfb2f((unsigned)Llds[k][lane]);
        uint2 vv = *(const uint2*)&stv[sp * VSTR + d0];
        o0 += e * bf2f_lo(vv.x);
        o1 += e * bf2f_hi(vv.x);
        o2 += e * bf2f_lo(vv.y);
        o3 += e * bf2f_hi(vv.y);
    }
    const size_t ob = ((size_t)(b * NH + n) * HD + d0) * HW + pix;
    out[ob]          = o0 * inv;
    out[ob + HW]     = o1 * inv;
    out[ob + 2 * HW] = o2 * inv;
    out[ob + 3 * HW] = o3 * inv;
}

extern "C" void kernel_launch(void* const* d_in, const int* in_sizes, int n_in,
                              void* d_out, int out_size, void* d_ws, size_t ws_size,
                              hipStream_t stream) {
    const float* x     = (const float*)d_in[0];
    const float* Wk    = (const float*)d_in[1];
    const float* Wq    = (const float*)d_in[2];
    const float* Wv    = (const float*)d_in[3];
    const float* rel_h = (const float*)d_in[4];
    const float* rel_w = (const float*)d_in[5];

    char* wsb = (char*)d_ws;
    float*          kmap = (float*)wsb;
    unsigned short* qmap = (unsigned short*)(wsb + QOFFB);
    unsigned short* vmap = (unsigned short*)(wsb + VOFFB);
    unsigned short* xh   = (unsigned short*)(wsb + XHOFFB);
    unsigned short* xl   = (unsigned short*)(wsb + XLOFFB);

    // W split scratch lives in d_out; attn fully overwrites d_out afterwards.
    unsigned short* whi = (unsigned short*)d_out;
    unsigned short* wlo = whi + WELEM;
    float* out = (float*)d_out;

    hipLaunchKernelGGL(xt_kernel,  dim3(49, 8, 2), dim3(256), 0, stream, x, xh, xl);
    hipLaunchKernelGGL(wbf_kernel, dim3(96),       dim3(256), 0, stream,
                       Wk, Wq, Wv, whi, wlo);
    hipLaunchKernelGGL(proj_kernel, dim3(49, 12),  dim3(512), 0, stream,
                       xh, xl, whi, wlo, kmap, qmap, vmap);
    hipLaunchKernelGGL(attn_kernel, dim3(784),     dim3(512), 0, stream,
                       kmap, qmap, vmap, rel_h, rel_w, out);
}

// Round 7
// 50.661 us; speedup vs baseline: 1.7640x; 1.0225x over previous
//
#include <hip/hip_runtime.h>
#include <hip/hip_bf16.h>

#define HW   3136   // 56*56
#define WID  56
#define CIN  256
#define NH   8
#define HD   32
#define KK   49
#define NW   8

// ws layout (byte offsets):
//   kmap  f32  [2*NH*HW*HD] @ 0
//   qmap  bf16              @ 6,422,528
//   vmap  bf16              @ 9,633,792
//   xT_hi bf16 [2*HW*CIN]   @ 12,845,056
//   xT_lo bf16              @ 16,056,320   (end 19,267,584)
#define MAPN  (2 * NH * HW * HD)
#define QOFFB 6422528
#define VOFFB 9633792
#define XHOFFB 12845056
#define XLOFFB 16056320
// W split lives in d_out (ushort): whi @ 0, wlo @ 768*256; attn overwrites after.
#define WELEM (768 * 256)

#define SROWS 196   // 14*14 staged halo window
#define VSTR  40    // ushorts per staged row (80 B stride, bank-balanced for b128)

typedef short  bf16x8 __attribute__((ext_vector_type(8)));
typedef float  f32x4  __attribute__((ext_vector_type(4)));

__device__ __forceinline__ unsigned f2bf(float x) {        // RNE f32->bf16 bits
    unsigned u = __float_as_uint(x);
    return (u + 0x7fffu + ((u >> 16) & 1u)) >> 16;
}
__device__ __forceinline__ float bfb2f(unsigned h)  { return __uint_as_float(h << 16); }
__device__ __forceinline__ float bf2f_lo(unsigned u){ return __uint_as_float(u << 16); }
__device__ __forceinline__ float bf2f_hi(unsigned u){ return __uint_as_float(u & 0xffff0000u); }

// ---------------------------------------------------------------------------
// xt_kernel: x[b][c][p] f32 -> xT_hi/xT_lo[(b*HW+p)*CIN + c] bf16 (transpose+split)
// ---------------------------------------------------------------------------
__global__ __launch_bounds__(256) void xt_kernel(
    const float* __restrict__ x,
    unsigned short* __restrict__ xh, unsigned short* __restrict__ xl)
{
    __shared__ float xs[32][65];
    const int b  = blockIdx.z;
    const int c0 = blockIdx.y * 32;
    const int p0 = blockIdx.x * 64;
    const int t  = threadIdx.x;
    const int pl = t & 63, cb = t >> 6;
    #pragma unroll
    for (int i = 0; i < 8; ++i)
        xs[cb + 4 * i][pl] = x[(size_t)(b * CIN + c0 + cb + 4 * i) * HW + p0 + pl];
    __syncthreads();
    const int pw = t >> 2, cg = t & 3;
    unsigned h[8], l[8];
    #pragma unroll
    for (int e = 0; e < 8; ++e) {
        float f = xs[cg * 8 + e][pw];
        h[e] = f2bf(f);
        l[e] = f2bf(f - bfb2f(h[e]));
    }
    uint4 uh = make_uint4(h[0] | (h[1] << 16), h[2] | (h[3] << 16),
                          h[4] | (h[5] << 16), h[6] | (h[7] << 16));
    uint4 ul = make_uint4(l[0] | (l[1] << 16), l[2] | (l[3] << 16),
                          l[4] | (l[5] << 16), l[6] | (l[7] << 16));
    const size_t idx = (size_t)(b * HW + p0 + pw) * CIN + c0 + cg * 8;
    *(uint4*)&xh[idx] = uh;
    *(uint4*)&xl[idx] = ul;
}

// ---------------------------------------------------------------------------
// wbf_kernel: Wk|Wq|Wv f32 [256][256] -> Whi/Wlo bf16 [768][256] (in d_out)
// ---------------------------------------------------------------------------
__global__ __launch_bounds__(256) void wbf_kernel(
    const float* __restrict__ Wk, const float* __restrict__ Wq,
    const float* __restrict__ Wv,
    unsigned short* __restrict__ whi, unsigned short* __restrict__ wlo)
{
    const int tid  = blockIdx.x * 256 + threadIdx.x;   // 0..24575
    const int mrow = tid >> 5, cg = tid & 31;
    const int proj = mrow >> 8, msub = mrow & 255;
    const float* Wp  = (proj == 0) ? Wk : (proj == 1 ? Wq : Wv);
    const float* src = Wp + (size_t)msub * CIN + cg * 8;
    float f[8];
    *(float4*)&f[0] = *(const float4*)src;
    *(float4*)&f[4] = *(const float4*)(src + 4);
    unsigned h[8], l[8];
    #pragma unroll
    for (int e = 0; e < 8; ++e) {
        h[e] = f2bf(f[e]);
        l[e] = f2bf(f[e] - bfb2f(h[e]));
    }
    uint4 uh = make_uint4(h[0] | (h[1] << 16), h[2] | (h[3] << 16),
                          h[4] | (h[5] << 16), h[6] | (h[7] << 16));
    uint4 ul = make_uint4(l[0] | (l[1] << 16), l[2] | (l[3] << 16),
                          l[4] | (l[5] << 16), l[6] | (l[7] << 16));
    *(uint4*)&whi[(size_t)mrow * CIN + cg * 8] = uh;
    *(uint4*)&wlo[(size_t)mrow * CIN + cg * 8] = ul;
}

// ---------------------------------------------------------------------------
// proj_kernel (split-bf16 MFMA, LDS-fed, T14 prefetch):
//   OUT[m][row] = sum_c W[m][c]*xT[row][c];  OUT = Whi*xhi + Whi*xlo + Wlo*xhi
// Block: 512 thr = 8 waves (2m x 4p), tile 64 m x 128 pixel-rows, BK=64.
// Next K-step's global loads issued right after the LDS writes -> latency
// hides under the 24 MFMAs of the current step.
// ---------------------------------------------------------------------------
__global__ __launch_bounds__(512, 4) void proj_kernel(
    const unsigned short* __restrict__ xh,
    const unsigned short* __restrict__ xl,
    const unsigned short* __restrict__ whi,
    const unsigned short* __restrict__ wlo,
    float* __restrict__ kmap,
    unsigned short* __restrict__ qmap,
    unsigned short* __restrict__ vmap)
{
    __shared__ unsigned short Xh[128 * 64];   // 16 KB
    __shared__ unsigned short Xl[128 * 64];   // 16 KB
    __shared__ unsigned short Wh[64 * 64];    //  8 KB
    __shared__ unsigned short Wl[64 * 64];    //  8 KB

    const int pr0 = blockIdx.x * 128;        // global pixel-row base
    const int m0  = blockIdx.y * 64;
    const int proj  = m0 >> 8;               // block-uniform
    const int msub0 = m0 & 255;

    const int t    = threadIdx.x;
    const int lane = t & 63;
    const int w    = t >> 6;
    const int wm   = (w >> 2) << 5;          // 0,32
    const int wp   = (w & 3) << 5;           // 0,32,64,96
    const int l15  = lane & 15;
    const int kg   = lane >> 4;
    const unsigned sz = (unsigned)(l15 & 7) << 4;

    f32x4 acc00 = {0.f, 0.f, 0.f, 0.f};
    f32x4 acc01 = acc00, acc10 = acc00, acc11 = acc00;

    // staging geometry (fixed per thread)
    const int srow  = t >> 3;                // 0..63
    const int scg   = t & 7;                 // 16B chunk within 64-c row
    const unsigned woff  = (unsigned)(srow * 128 + ((scg * 16) ^ ((srow & 7) << 4)));
    const int xrow1 = srow + 64;
    const unsigned xoff1 = (unsigned)(xrow1 * 128 + ((scg * 16) ^ ((xrow1 & 7) << 4)));

    // register prefetch buffers
    uint4 rWh, rWl, rXh0, rXl0, rXh1, rXl1;
    {
        size_t wg  = (size_t)(m0 + srow) * CIN + scg * 8;
        size_t xg0 = (size_t)(pr0 + srow) * CIN + scg * 8;
        size_t xg1 = xg0 + (size_t)64 * CIN;
        rWh  = *(const uint4*)&whi[wg];
        rWl  = *(const uint4*)&wlo[wg];
        rXh0 = *(const uint4*)&xh[xg0];
        rXl0 = *(const uint4*)&xl[xg0];
        rXh1 = *(const uint4*)&xh[xg1];
        rXl1 = *(const uint4*)&xl[xg1];
    }

    for (int c0 = 0; c0 < CIN; c0 += 64) {
        if (c0) __syncthreads();             // previous compute done reading LDS
        *(uint4*)((char*)Wh + woff)  = rWh;
        *(uint4*)((char*)Wl + woff)  = rWl;
        *(uint4*)((char*)Xh + woff)  = rXh0;
        *(uint4*)((char*)Xl + woff)  = rXl0;
        *(uint4*)((char*)Xh + xoff1) = rXh1;
        *(uint4*)((char*)Xl + xoff1) = rXl1;
        if (c0 + 64 < CIN) {                 // prefetch next K-step (flies under MFMA)
            size_t wg  = (size_t)(m0 + srow) * CIN + (c0 + 64) + scg * 8;
            size_t xg0 = (size_t)(pr0 + srow) * CIN + (c0 + 64) + scg * 8;
            size_t xg1 = xg0 + (size_t)64 * CIN;
            rWh  = *(const uint4*)&whi[wg];
            rWl  = *(const uint4*)&wlo[wg];
            rXh0 = *(const uint4*)&xh[xg0];
            rXl0 = *(const uint4*)&xl[xg0];
            rXh1 = *(const uint4*)&xh[xg1];
            rXl1 = *(const uint4*)&xl[xg1];
        }
        __syncthreads();

        #pragma unroll
        for (int kk = 0; kk < 2; ++kk) {
            const unsigned cb = ((unsigned)(kk * 64 + kg * 16)) ^ sz;
            const char* whb = (const char*)Wh + cb;
            const char* wlb = (const char*)Wl + cb;
            const char* xhb = (const char*)Xh + cb;
            const char* xlb = (const char*)Xl + cb;
            bf16x8 ah0 = *(const bf16x8*)(whb + (wm + l15) * 128);
            bf16x8 ah1 = *(const bf16x8*)(whb + (wm + 16 + l15) * 128);
            bf16x8 al0 = *(const bf16x8*)(wlb + (wm + l15) * 128);
            bf16x8 al1 = *(const bf16x8*)(wlb + (wm + 16 + l15) * 128);
            bf16x8 bh0 = *(const bf16x8*)(xhb + (wp + l15) * 128);
            bf16x8 bh1 = *(const bf16x8*)(xhb + (wp + 16 + l15) * 128);
            bf16x8 bl0 = *(const bf16x8*)(xlb + (wp + l15) * 128);
            bf16x8 bl1 = *(const bf16x8*)(xlb + (wp + 16 + l15) * 128);
            acc00 = __builtin_amdgcn_mfma_f32_16x16x32_bf16(ah0, bh0, acc00, 0, 0, 0);
            acc01 = __builtin_amdgcn_mfma_f32_16x16x32_bf16(ah0, bh1, acc01, 0, 0, 0);
            acc10 = __builtin_amdgcn_mfma_f32_16x16x32_bf16(ah1, bh0, acc10, 0, 0, 0);
            acc11 = __builtin_amdgcn_mfma_f32_16x16x32_bf16(ah1, bh1, acc11, 0, 0, 0);
            acc00 = __builtin_amdgcn_mfma_f32_16x16x32_bf16(ah0, bl0, acc00, 0, 0, 0);
            acc01 = __builtin_amdgcn_mfma_f32_16x16x32_bf16(ah0, bl1, acc01, 0, 0, 0);
            acc10 = __builtin_amdgcn_mfma_f32_16x16x32_bf16(ah1, bl0, acc10, 0, 0, 0);
            acc11 = __builtin_amdgcn_mfma_f32_16x16x32_bf16(ah1, bl1, acc11, 0, 0, 0);
            acc00 = __builtin_amdgcn_mfma_f32_16x16x32_bf16(al0, bh0, acc00, 0, 0, 0);
            acc01 = __builtin_amdgcn_mfma_f32_16x16x32_bf16(al0, bh1, acc01, 0, 0, 0);
            acc10 = __builtin_amdgcn_mfma_f32_16x16x32_bf16(al1, bh0, acc10, 0, 0, 0);
            acc11 = __builtin_amdgcn_mfma_f32_16x16x32_bf16(al1, bh1, acc11, 0, 0, 0);
        }
    }

    // epilogue: each lane's f32x4 = 4 consecutive m (=d) for one pixel-row
    #define ST(ACC, MI, PI) { \
        int prow = pr0 + wp + (PI) * 16 + l15; \
        int bb = (prow >= HW) ? 1 : 0; \
        int pp = prow - bb * HW; \
        int msub = msub0 + wm + (MI) * 16 + kg * 4; \
        size_t base = ((size_t)(bb * NH + (msub >> 5)) * HW + pp) * HD + (msub & 31); \
        if (proj == 0) { \
            *(float4*)&kmap[base] = make_float4(ACC[0], ACC[1], ACC[2], ACC[3]); \
        } else { \
            uint2 u; \
            u.x = f2bf(ACC[0]) | (f2bf(ACC[1]) << 16); \
            u.y = f2bf(ACC[2]) | (f2bf(ACC[3]) << 16); \
            unsigned short* mp = (proj == 1) ? qmap : vmap; \
            *(uint2*)&mp[base] = u; } }
    ST(acc00, 0, 0) ST(acc01, 0, 1) ST(acc10, 1, 0) ST(acc11, 1, 1)
    #undef ST
}

// ---------------------------------------------------------------------------
// attn_kernel: block = (b, n, 8x8 pixel tile), 512 threads, 2 barriers.
// q and v staged bf16 (copy); local-max softmax: wave w stores e=exp(l-m_w),
// (m_w, sum_w); after ONE barrier every thread merges the 8 partials and
// folds exp(m_w-m)/s into fw[w] used by PV (k&7 is compile-time).
// ---------------------------------------------------------------------------
__global__ __launch_bounds__(512, 4) void attn_kernel(
    const float* __restrict__ kmap,
    const unsigned short* __restrict__ qmap,
    const unsigned short* __restrict__ vmap,
    const float* __restrict__ rel_h,
    const float* __restrict__ rel_w,
    float* __restrict__ out)
{
    __shared__ unsigned short stq[SROWS * VSTR];   // 15680 B
    __shared__ unsigned short stv[SROWS * VSTR];   // 15680 B
    __shared__ unsigned short Llds[KK][64];        //  6272 B
    __shared__ float          rhw[14][64];         //  3584 B
    __shared__ float          mpart[NW][64];       //  2048 B
    __shared__ float          spart[NW][64];       //  2048 B  (total 45312 B)

    const int bid = blockIdx.x;
    const int swz = (bid & 7) * 98 + (bid >> 3);   // XCD-bijective (784 = 8*98)
    const int b    = swz / 392;
    const int rem  = swz - b * 392;
    const int n    = rem / 49;
    const int tile = rem - n * 49;
    const int ty0  = (tile / 7) * 8;
    const int tx0  = (tile % 7) * 8;

    const int t    = threadIdx.x;
    const int lane = t & 63;
    const int w    = t >> 6;
    const int py   = lane >> 3;
    const int px   = lane & 7;
    const int pix  = (ty0 + py) * WID + tx0 + px;

    const size_t mb = (size_t)(b * NH + n) * HW;

    // ---- stage q and v (bf16 straight copy) ----
    #pragma unroll
    for (int kk = 0; kk < 2; ++kk) {
        int f = t + kk * 512;
        if (f < SROWS * 4) {
            int sp = f >> 2, ch = f & 3;
            int sy = sp / 14, sx = sp - sy * 14;
            int gy = ty0 + sy - 3, gx = tx0 + sx - 3;
            uint4 q = make_uint4(0, 0, 0, 0), v = make_uint4(0, 0, 0, 0);
            if ((unsigned)gy < 56u && (unsigned)gx < 56u) {
                size_t rec = (mb + gy * WID + gx) * HD + ch * 8;
                q = *(const uint4*)&qmap[rec];
                v = *(const uint4*)&vmap[rec];
            }
            *(uint4*)&stq[sp * VSTR + ch * 8] = q;
            *(uint4*)&stv[sp * VSTR + ch * 8] = v;
        }
    }

    // ---- center key vector (f32) ----
    float kc[HD];
    const size_t krec = (mb + pix) * HD;
    #pragma unroll
    for (int c4 = 0; c4 < 8; ++c4) {
        float4 kv = *(const float4*)&kmap[krec + c4 * 4];
        kc[c4 * 4 + 0] = kv.x; kc[c4 * 4 + 1] = kv.y;
        kc[c4 * 4 + 2] = kv.z; kc[c4 * 4 + 3] = kv.w;
    }

    // ---- rel bias dots, once per block (waves 0..6) ----
    if (w < 7) {
        float a = 0.f, c = 0.f;
        #pragma unroll
        for (int dd = 0; dd < 16; ++dd) {
            a += rel_h[(n * 7 + w) * 16 + dd] * kc[dd];
            c += rel_w[(n * 7 + w) * 16 + dd] * kc[16 + dd];
        }
        rhw[w][lane]     = a;
        rhw[7 + w][lane] = c;
    }
    __syncthreads();   // barrier 1: staging + rhw visible

    // ---- QK: wave w owns cells k = w + 8c; local-max softmax ----
    const int spc = py * 14 + px;
    float l[7];
    float lm = -1e30f;
    #pragma unroll
    for (int c = 0; c < 7; ++c) {
        const int k = w + c * NW;
        if (k < KK) {                       // wave-uniform
            int i = k / 7, j = k - i * 7;
            const unsigned short* qr = &stq[(spc + i * 14 + j) * VSTR];
            float dot = 0.f;
            #pragma unroll
            for (int c4 = 0; c4 < 4; ++c4) {
                uint4 qv = *(const uint4*)&qr[c4 * 8];
                dot += kc[c4*8+0] * bf2f_lo(qv.x) + kc[c4*8+1] * bf2f_hi(qv.x)
                     + kc[c4*8+2] * bf2f_lo(qv.y) + kc[c4*8+3] * bf2f_hi(qv.y)
                     + kc[c4*8+4] * bf2f_lo(qv.z) + kc[c4*8+5] * bf2f_hi(qv.z)
                     + kc[c4*8+6] * bf2f_lo(qv.w) + kc[c4*8+7] * bf2f_hi(qv.w);
            }
            float lv = rhw[i][lane] + rhw[7 + j][lane] + dot;
            l[c] = lv;
            lm = fmaxf(lm, lv);
        } else {
            l[c] = -1e30f;
        }
    }
    float ls = 0.f;
    #pragma unroll
    for (int c = 0; c < 7; ++c) {
        const int k = w + c * NW;
        if (k < KK) {
            float e = __expf(l[c] - lm);
            ls += e;
            Llds[k][lane] = (unsigned short)f2bf(e);
        }
    }
    mpart[w][lane] = lm;
    spart[w][lane] = ls;
    __syncthreads();   // barrier 2: partials + Llds visible

    // ---- merge partials: m, s, per-wave factors fw[] (inv folded in) ----
    float m = mpart[0][lane];
    #pragma unroll
    for (int ww = 1; ww < NW; ++ww) m = fmaxf(m, mpart[ww][lane]);
    float fw[NW];
    float s = 0.f;
    #pragma unroll
    for (int ww = 0; ww < NW; ++ww) {
        float f = __expf(mpart[ww][lane] - m);
        s += spart[ww][lane] * f;
        fw[ww] = f;
    }
    const float inv = 1.f / s;
    #pragma unroll
    for (int ww = 0; ww < NW; ++ww) fw[ww] *= inv;

    // ---- PV: wave w owns d = 4w..4w+3 ----
    const int d0 = w * 4;
    float o0 = 0.f, o1 = 0.f, o2 = 0.f, o3 = 0.f;
    #pragma unroll
    for (int k = 0; k < KK; ++k) {
        const int i = k / 7, j = k - i * 7;
        int sp = spc + i * 14 + j;
        float a = bfb2f((unsigned)Llds[k][lane]) * fw[k & 7];
        uint2 vv = *(const uint2*)&stv[sp * VSTR + d0];
        o0 += a * bf2f_lo(vv.x);
        o1 += a * bf2f_hi(vv.x);
        o2 += a * bf2f_lo(vv.y);
        o3 += a * bf2f_hi(vv.y);
    }
    const size_t ob = ((size_t)(b * NH + n) * HD + d0) * HW + pix;
    out[ob]          = o0;
    out[ob + HW]     = o1;
    out[ob + 2 * HW] = o2;
    out[ob + 3 * HW] = o3;
}

extern "C" void kernel_launch(void* const* d_in, const int* in_sizes, int n_in,
                              void* d_out, int out_size, void* d_ws, size_t ws_size,
                              hipStream_t stream) {
    const float* x     = (const float*)d_in[0];
    const float* Wk    = (const float*)d_in[1];
    const float* Wq    = (const float*)d_in[2];
    const float* Wv    = (const float*)d_in[3];
    const float* rel_h = (const float*)d_in[4];
    const float* rel_w = (const float*)d_in[5];

    char* wsb = (char*)d_ws;
    float*          kmap = (float*)wsb;
    unsigned short* qmap = (unsigned short*)(wsb + QOFFB);
    unsigned short* vmap = (unsigned short*)(wsb + VOFFB);
    unsigned short* xh   = (unsigned short*)(wsb + XHOFFB);
    unsigned short* xl   = (unsigned short*)(wsb + XLOFFB);

    // W split scratch lives in d_out; attn fully overwrites d_out afterwards.
    unsigned short* whi = (unsigned short*)d_out;
    unsigned short* wlo = whi + WELEM;
    float* out = (float*)d_out;

    hipLaunchKernelGGL(xt_kernel,  dim3(49, 8, 2), dim3(256), 0, stream, x, xh, xl);
    hipLaunchKernelGGL(wbf_kernel, dim3(96),       dim3(256), 0, stream,
                       Wk, Wq, Wv, whi, wlo);
    hipLaunchKernelGGL(proj_kernel, dim3(49, 12),  dim3(512), 0, stream,
                       xh, xl, whi, wlo, kmap, qmap, vmap);
    hipLaunchKernelGGL(attn_kernel, dim3(784),     dim3(512), 0, stream,
                       kmap, qmap, vmap, rel_h, rel_w, out);
}

// Round 8
// 49.196 us; speedup vs baseline: 1.8165x; 1.0298x over previous
//
#include <hip/hip_runtime.h>
#include <hip/hip_bf16.h>

#define HW   3136   // 56*56
#define WID  56
#define CIN  256
#define NH   8
#define HD   32
#define KK   49
#define NW   8

// ws layout (byte offsets):
//   kmap  f32  [2*NH*HW*HD] @ 0
//   qmap  bf16              @ 6,422,528
//   vmap  bf16              @ 9,633,792
//   xT_hi bf16 [2*HW*CIN]   @ 12,845,056
//   xT_lo bf16              @ 16,056,320   (end 19,267,584)
#define MAPN  (2 * NH * HW * HD)
#define QOFFB 6422528
#define VOFFB 9633792
#define XHOFFB 12845056
#define XLOFFB 16056320
// W split lives in d_out (ushort): whi @ 0, wlo @ 768*256; attn overwrites after.
#define WELEM (768 * 256)

#define SROWS 196   // 14*14 staged halo window
#define VSTR  40    // ushorts per staged row (80 B stride, bank-balanced for b128)

typedef short  bf16x8 __attribute__((ext_vector_type(8)));
typedef float  f32x4  __attribute__((ext_vector_type(4)));

__device__ __forceinline__ unsigned f2bf(float x) {        // RNE f32->bf16 bits
    unsigned u = __float_as_uint(x);
    return (u + 0x7fffu + ((u >> 16) & 1u)) >> 16;
}
__device__ __forceinline__ float bfb2f(unsigned h)  { return __uint_as_float(h << 16); }
__device__ __forceinline__ float bf2f_lo(unsigned u){ return __uint_as_float(u << 16); }
__device__ __forceinline__ float bf2f_hi(unsigned u){ return __uint_as_float(u & 0xffff0000u); }

// ---------------------------------------------------------------------------
// prep_kernel: blocks 0..783 = x transpose+split; blocks 784..879 = W split.
// ---------------------------------------------------------------------------
__global__ __launch_bounds__(256) void prep_kernel(
    const float* __restrict__ x,
    const float* __restrict__ Wk, const float* __restrict__ Wq,
    const float* __restrict__ Wv,
    unsigned short* __restrict__ xh, unsigned short* __restrict__ xl,
    unsigned short* __restrict__ whi, unsigned short* __restrict__ wlo)
{
    __shared__ float xs[32][65];
    const int bid = blockIdx.x;
    const int t   = threadIdx.x;

    if (bid < 784) {
        // ---- xt part: x[b][c][p] f32 -> xT hi/lo bf16 ----
        const int p0 = (bid % 49) * 64;
        const int c0 = ((bid / 49) & 7) * 32;
        const int b  = bid / 392;
        const int pl = t & 63, cb = t >> 6;
        #pragma unroll
        for (int i = 0; i < 8; ++i)
            xs[cb + 4 * i][pl] = x[(size_t)(b * CIN + c0 + cb + 4 * i) * HW + p0 + pl];
        __syncthreads();
        const int pw = t >> 2, cg = t & 3;
        unsigned h[8], l[8];
        #pragma unroll
        for (int e = 0; e < 8; ++e) {
            float f = xs[cg * 8 + e][pw];
            h[e] = f2bf(f);
            l[e] = f2bf(f - bfb2f(h[e]));
        }
        uint4 uh = make_uint4(h[0] | (h[1] << 16), h[2] | (h[3] << 16),
                              h[4] | (h[5] << 16), h[6] | (h[7] << 16));
        uint4 ul = make_uint4(l[0] | (l[1] << 16), l[2] | (l[3] << 16),
                              l[4] | (l[5] << 16), l[6] | (l[7] << 16));
        const size_t idx = (size_t)(b * HW + p0 + pw) * CIN + c0 + cg * 8;
        *(uint4*)&xh[idx] = uh;
        *(uint4*)&xl[idx] = ul;
    } else {
        // ---- wbf part: Wk|Wq|Wv -> Whi/Wlo bf16 [768][256] ----
        const int tid  = (bid - 784) * 256 + t;        // 0..24575
        const int mrow = tid >> 5, cg = tid & 31;
        const int proj = mrow >> 8, msub = mrow & 255;
        const float* Wp  = (proj == 0) ? Wk : (proj == 1 ? Wq : Wv);
        const float* src = Wp + (size_t)msub * CIN + cg * 8;
        float f[8];
        *(float4*)&f[0] = *(const float4*)src;
        *(float4*)&f[4] = *(const float4*)(src + 4);
        unsigned h[8], l[8];
        #pragma unroll
        for (int e = 0; e < 8; ++e) {
            h[e] = f2bf(f[e]);
            l[e] = f2bf(f[e] - bfb2f(h[e]));
        }
        uint4 uh = make_uint4(h[0] | (h[1] << 16), h[2] | (h[3] << 16),
                              h[4] | (h[5] << 16), h[6] | (h[7] << 16));
        uint4 ul = make_uint4(l[0] | (l[1] << 16), l[2] | (l[3] << 16),
                              l[4] | (l[5] << 16), l[6] | (l[7] << 16));
        *(uint4*)&whi[(size_t)mrow * CIN + cg * 8] = uh;
        *(uint4*)&wlo[(size_t)mrow * CIN + cg * 8] = ul;
    }
}

// ---------------------------------------------------------------------------
// proj_kernel (split-bf16 MFMA, LDS-fed, register prefetch):
//   OUT[m][row] = sum_c W[m][c]*xT[row][c];  OUT = Whi*xhi + Whi*xlo + Wlo*xhi
// ---------------------------------------------------------------------------
__global__ __launch_bounds__(512, 4) void proj_kernel(
    const unsigned short* __restrict__ xh,
    const unsigned short* __restrict__ xl,
    const unsigned short* __restrict__ whi,
    const unsigned short* __restrict__ wlo,
    float* __restrict__ kmap,
    unsigned short* __restrict__ qmap,
    unsigned short* __restrict__ vmap)
{
    __shared__ unsigned short Xh[128 * 64];   // 16 KB
    __shared__ unsigned short Xl[128 * 64];   // 16 KB
    __shared__ unsigned short Wh[64 * 64];    //  8 KB
    __shared__ unsigned short Wl[64 * 64];    //  8 KB

    const int pr0 = blockIdx.x * 128;        // global pixel-row base
    const int m0  = blockIdx.y * 64;
    const int proj  = m0 >> 8;               // block-uniform
    const int msub0 = m0 & 255;

    const int t    = threadIdx.x;
    const int lane = t & 63;
    const int w    = t >> 6;
    const int wm   = (w >> 2) << 5;          // 0,32
    const int wp   = (w & 3) << 5;           // 0,32,64,96
    const int l15  = lane & 15;
    const int kg   = lane >> 4;
    const unsigned sz = (unsigned)(l15 & 7) << 4;

    f32x4 acc00 = {0.f, 0.f, 0.f, 0.f};
    f32x4 acc01 = acc00, acc10 = acc00, acc11 = acc00;

    const int srow  = t >> 3;                // 0..63
    const int scg   = t & 7;                 // 16B chunk within 64-c row
    const unsigned woff  = (unsigned)(srow * 128 + ((scg * 16) ^ ((srow & 7) << 4)));
    const int xrow1 = srow + 64;
    const unsigned xoff1 = (unsigned)(xrow1 * 128 + ((scg * 16) ^ ((xrow1 & 7) << 4)));

    uint4 rWh, rWl, rXh0, rXl0, rXh1, rXl1;
    {
        size_t wg  = (size_t)(m0 + srow) * CIN + scg * 8;
        size_t xg0 = (size_t)(pr0 + srow) * CIN + scg * 8;
        size_t xg1 = xg0 + (size_t)64 * CIN;
        rWh  = *(const uint4*)&whi[wg];
        rWl  = *(const uint4*)&wlo[wg];
        rXh0 = *(const uint4*)&xh[xg0];
        rXl0 = *(const uint4*)&xl[xg0];
        rXh1 = *(const uint4*)&xh[xg1];
        rXl1 = *(const uint4*)&xl[xg1];
    }

    for (int c0 = 0; c0 < CIN; c0 += 64) {
        if (c0) __syncthreads();
        *(uint4*)((char*)Wh + woff)  = rWh;
        *(uint4*)((char*)Wl + woff)  = rWl;
        *(uint4*)((char*)Xh + woff)  = rXh0;
        *(uint4*)((char*)Xl + woff)  = rXl0;
        *(uint4*)((char*)Xh + xoff1) = rXh1;
        *(uint4*)((char*)Xl + xoff1) = rXl1;
        if (c0 + 64 < CIN) {
            size_t wg  = (size_t)(m0 + srow) * CIN + (c0 + 64) + scg * 8;
            size_t xg0 = (size_t)(pr0 + srow) * CIN + (c0 + 64) + scg * 8;
            size_t xg1 = xg0 + (size_t)64 * CIN;
            rWh  = *(const uint4*)&whi[wg];
            rWl  = *(const uint4*)&wlo[wg];
            rXh0 = *(const uint4*)&xh[xg0];
            rXl0 = *(const uint4*)&xl[xg0];
            rXh1 = *(const uint4*)&xh[xg1];
            rXl1 = *(const uint4*)&xl[xg1];
        }
        __syncthreads();

        #pragma unroll
        for (int kk = 0; kk < 2; ++kk) {
            const unsigned cb = ((unsigned)(kk * 64 + kg * 16)) ^ sz;
            const char* whb = (const char*)Wh + cb;
            const char* wlb = (const char*)Wl + cb;
            const char* xhb = (const char*)Xh + cb;
            const char* xlb = (const char*)Xl + cb;
            bf16x8 ah0 = *(const bf16x8*)(whb + (wm + l15) * 128);
            bf16x8 ah1 = *(const bf16x8*)(whb + (wm + 16 + l15) * 128);
            bf16x8 al0 = *(const bf16x8*)(wlb + (wm + l15) * 128);
            bf16x8 al1 = *(const bf16x8*)(wlb + (wm + 16 + l15) * 128);
            bf16x8 bh0 = *(const bf16x8*)(xhb + (wp + l15) * 128);
            bf16x8 bh1 = *(const bf16x8*)(xhb + (wp + 16 + l15) * 128);
            bf16x8 bl0 = *(const bf16x8*)(xlb + (wp + l15) * 128);
            bf16x8 bl1 = *(const bf16x8*)(xlb + (wp + 16 + l15) * 128);
            acc00 = __builtin_amdgcn_mfma_f32_16x16x32_bf16(ah0, bh0, acc00, 0, 0, 0);
            acc01 = __builtin_amdgcn_mfma_f32_16x16x32_bf16(ah0, bh1, acc01, 0, 0, 0);
            acc10 = __builtin_amdgcn_mfma_f32_16x16x32_bf16(ah1, bh0, acc10, 0, 0, 0);
            acc11 = __builtin_amdgcn_mfma_f32_16x16x32_bf16(ah1, bh1, acc11, 0, 0, 0);
            acc00 = __builtin_amdgcn_mfma_f32_16x16x32_bf16(ah0, bl0, acc00, 0, 0, 0);
            acc01 = __builtin_amdgcn_mfma_f32_16x16x32_bf16(ah0, bl1, acc01, 0, 0, 0);
            acc10 = __builtin_amdgcn_mfma_f32_16x16x32_bf16(ah1, bl0, acc10, 0, 0, 0);
            acc11 = __builtin_amdgcn_mfma_f32_16x16x32_bf16(ah1, bl1, acc11, 0, 0, 0);
            acc00 = __builtin_amdgcn_mfma_f32_16x16x32_bf16(al0, bh0, acc00, 0, 0, 0);
            acc01 = __builtin_amdgcn_mfma_f32_16x16x32_bf16(al0, bh1, acc01, 0, 0, 0);
            acc10 = __builtin_amdgcn_mfma_f32_16x16x32_bf16(al1, bh0, acc10, 0, 0, 0);
            acc11 = __builtin_amdgcn_mfma_f32_16x16x32_bf16(al1, bh1, acc11, 0, 0, 0);
        }
    }

    #define ST(ACC, MI, PI) { \
        int prow = pr0 + wp + (PI) * 16 + l15; \
        int bb = (prow >= HW) ? 1 : 0; \
        int pp = prow - bb * HW; \
        int msub = msub0 + wm + (MI) * 16 + kg * 4; \
        size_t base = ((size_t)(bb * NH + (msub >> 5)) * HW + pp) * HD + (msub & 31); \
        if (proj == 0) { \
            *(float4*)&kmap[base] = make_float4(ACC[0], ACC[1], ACC[2], ACC[3]); \
        } else { \
            uint2 u; \
            u.x = f2bf(ACC[0]) | (f2bf(ACC[1]) << 16); \
            u.y = f2bf(ACC[2]) | (f2bf(ACC[3]) << 16); \
            unsigned short* mp = (proj == 1) ? qmap : vmap; \
            *(uint2*)&mp[base] = u; } }
    ST(acc00, 0, 0) ST(acc01, 0, 1) ST(acc10, 1, 0) ST(acc11, 1, 1)
    #undef ST
}

// ---------------------------------------------------------------------------
// attn_kernel: block = (b, n, 8x8 pixel tile), 512 threads, 2 barriers.
// launch_bounds(512,6): ~85 VGPR cap -> 3 blocks/CU (LDS 45.3KB allows 3).
// All dot products manually split into independent partial accumulators.
// ---------------------------------------------------------------------------
__global__ __launch_bounds__(512, 6) void attn_kernel(
    const float* __restrict__ kmap,
    const unsigned short* __restrict__ qmap,
    const unsigned short* __restrict__ vmap,
    const float* __restrict__ rel_h,
    const float* __restrict__ rel_w,
    float* __restrict__ out)
{
    __shared__ unsigned short stq[SROWS * VSTR];   // 15680 B
    __shared__ unsigned short stv[SROWS * VSTR];   // 15680 B
    __shared__ unsigned short Llds[KK][64];        //  6272 B
    __shared__ float          rhw[14][64];         //  3584 B
    __shared__ float          mpart[NW][64];       //  2048 B
    __shared__ float          spart[NW][64];       //  2048 B  (total 45312 B)

    const int bid = blockIdx.x;
    const int swz = (bid & 7) * 98 + (bid >> 3);   // XCD-bijective (784 = 8*98)
    const int b    = swz / 392;
    const int rem  = swz - b * 392;
    const int n    = rem / 49;
    const int tile = rem - n * 49;
    const int ty0  = (tile / 7) * 8;
    const int tx0  = (tile % 7) * 8;

    const int t    = threadIdx.x;
    const int lane = t & 63;
    const int w    = t >> 6;
    const int py   = lane >> 3;
    const int px   = lane & 7;
    const int pix  = (ty0 + py) * WID + tx0 + px;

    const size_t mb = (size_t)(b * NH + n) * HW;

    // ---- center key vector first (feeds rel dots before barrier) ----
    float kc[HD];
    const size_t krec = (mb + pix) * HD;
    #pragma unroll
    for (int c4 = 0; c4 < 8; ++c4) {
        float4 kv = *(const float4*)&kmap[krec + c4 * 4];
        kc[c4 * 4 + 0] = kv.x; kc[c4 * 4 + 1] = kv.y;
        kc[c4 * 4 + 2] = kv.z; kc[c4 * 4 + 3] = kv.w;
    }

    // ---- stage q and v (bf16 straight copy) ----
    #pragma unroll
    for (int kk = 0; kk < 2; ++kk) {
        int f = t + kk * 512;
        if (f < SROWS * 4) {
            int sp = f >> 2, ch = f & 3;
            int sy = sp / 14, sx = sp - sy * 14;
            int gy = ty0 + sy - 3, gx = tx0 + sx - 3;
            uint4 q = make_uint4(0, 0, 0, 0), v = make_uint4(0, 0, 0, 0);
            if ((unsigned)gy < 56u && (unsigned)gx < 56u) {
                size_t rec = (mb + gy * WID + gx) * HD + ch * 8;
                q = *(const uint4*)&qmap[rec];
                v = *(const uint4*)&vmap[rec];
            }
            *(uint4*)&stq[sp * VSTR + ch * 8] = q;
            *(uint4*)&stv[sp * VSTR + ch * 8] = v;
        }
    }

    // ---- rel bias dots, once per block (waves 0..6), 2-way split ----
    if (w < 7) {
        float a0 = 0.f, a1 = 0.f, c0 = 0.f, c1 = 0.f;
        #pragma unroll
        for (int dd = 0; dd < 8; ++dd) {
            a0 += rel_h[(n * 7 + w) * 16 + dd]     * kc[dd];
            a1 += rel_h[(n * 7 + w) * 16 + 8 + dd] * kc[8 + dd];
            c0 += rel_w[(n * 7 + w) * 16 + dd]     * kc[16 + dd];
            c1 += rel_w[(n * 7 + w) * 16 + 8 + dd] * kc[24 + dd];
        }
        rhw[w][lane]     = a0 + a1;
        rhw[7 + w][lane] = c0 + c1;
    }
    __syncthreads();   // barrier 1: staging + rhw visible

    // ---- QK: wave w owns cells k = w + 8c; 4-way split dot; local max ----
    const int spc = py * 14 + px;
    float l[7];
    float lm = -1e30f;
    #pragma unroll
    for (int c = 0; c < 7; ++c) {
        const int k = w + c * NW;
        if (k < KK) {                       // wave-uniform
            int i = k / 7, j = k - i * 7;
            const unsigned short* qr = &stq[(spc + i * 14 + j) * VSTR];
            float d0 = 0.f, d1 = 0.f, d2 = 0.f, d3 = 0.f;
            #pragma unroll
            for (int c4 = 0; c4 < 4; ++c4) {
                uint4 qv = *(const uint4*)&qr[c4 * 8];
                float* dp = (c4 == 0) ? &d0 : (c4 == 1) ? &d1 : (c4 == 2) ? &d2 : &d3;
                float p0 = kc[c4*8+0] * bf2f_lo(qv.x) + kc[c4*8+1] * bf2f_hi(qv.x);
                float p1 = kc[c4*8+2] * bf2f_lo(qv.y) + kc[c4*8+3] * bf2f_hi(qv.y);
                float p2 = kc[c4*8+4] * bf2f_lo(qv.z) + kc[c4*8+5] * bf2f_hi(qv.z);
                float p3 = kc[c4*8+6] * bf2f_lo(qv.w) + kc[c4*8+7] * bf2f_hi(qv.w);
                *dp += (p0 + p1) + (p2 + p3);
            }
            float lv = (rhw[i][lane] + rhw[7 + j][lane]) + ((d0 + d1) + (d2 + d3));
            l[c] = lv;
            lm = fmaxf(lm, lv);
        } else {
            l[c] = -1e30f;
        }
    }
    float ls = 0.f;
    #pragma unroll
    for (int c = 0; c < 7; ++c) {
        const int k = w + c * NW;
        if (k < KK) {
            float e = __expf(l[c] - lm);
            ls += e;
            Llds[k][lane] = (unsigned short)f2bf(e);
        }
    }
    mpart[w][lane] = lm;
    spart[w][lane] = ls;
    __syncthreads();   // barrier 2: partials + Llds visible

    // ---- merge partials: m, s, per-wave factors fw[] (inv folded in) ----
    float m = mpart[0][lane];
    #pragma unroll
    for (int ww = 1; ww < NW; ++ww) m = fmaxf(m, mpart[ww][lane]);
    float fw[NW];
    float s = 0.f;
    #pragma unroll
    for (int ww = 0; ww < NW; ++ww) {
        float f = __expf(mpart[ww][lane] - m);
        s += spart[ww][lane] * f;
        fw[ww] = f;
    }
    const float inv = 1.f / s;
    #pragma unroll
    for (int ww = 0; ww < NW; ++ww) fw[ww] *= inv;

    // ---- PV: wave w owns d = 4w..4w+3 (4 independent chains) ----
    const int d0 = w * 4;
    float o0 = 0.f, o1 = 0.f, o2 = 0.f, o3 = 0.f;
    #pragma unroll
    for (int k = 0; k < KK; ++k) {
        const int i = k / 7, j = k - i * 7;
        int sp = spc + i * 14 + j;
        float a = bfb2f((unsigned)Llds[k][lane]) * fw[k & 7];
        uint2 vv = *(const uint2*)&stv[sp * VSTR + d0];
        o0 += a * bf2f_lo(vv.x);
        o1 += a * bf2f_hi(vv.x);
        o2 += a * bf2f_lo(vv.y);
        o3 += a * bf2f_hi(vv.y);
    }
    const size_t ob = ((size_t)(b * NH + n) * HD + d0) * HW + pix;
    out[ob]          = o0;
    out[ob + HW]     = o1;
    out[ob + 2 * HW] = o2;
    out[ob + 3 * HW] = o3;
}

extern "C" void kernel_launch(void* const* d_in, const int* in_sizes, int n_in,
                              void* d_out, int out_size, void* d_ws, size_t ws_size,
                              hipStream_t stream) {
    const float* x     = (const float*)d_in[0];
    const float* Wk    = (const float*)d_in[1];
    const float* Wq    = (const float*)d_in[2];
    const float* Wv    = (const float*)d_in[3];
    const float* rel_h = (const float*)d_in[4];
    const float* rel_w = (const float*)d_in[5];

    char* wsb = (char*)d_ws;
    float*          kmap = (float*)wsb;
    unsigned short* qmap = (unsigned short*)(wsb + QOFFB);
    unsigned short* vmap = (unsigned short*)(wsb + VOFFB);
    unsigned short* xh   = (unsigned short*)(wsb + XHOFFB);
    unsigned short* xl   = (unsigned short*)(wsb + XLOFFB);

    // W split scratch lives in d_out; attn fully overwrites d_out afterwards.
    unsigned short* whi = (unsigned short*)d_out;
    unsigned short* wlo = whi + WELEM;
    float* out = (float*)d_out;

    hipLaunchKernelGGL(prep_kernel, dim3(880),    dim3(256), 0, stream,
                       x, Wk, Wq, Wv, xh, xl, whi, wlo);
    hipLaunchKernelGGL(proj_kernel, dim3(49, 12), dim3(512), 0, stream,
                       xh, xl, whi, wlo, kmap, qmap, vmap);
    hipLaunchKernelGGL(attn_kernel, dim3(784),    dim3(512), 0, stream,
                       kmap, qmap, vmap, rel_h, rel_w, out);
}